// Round 1
// baseline (179.287 us; speedup 1.0000x reference)
//
#include <hip/hip_runtime.h>

#define ENTRY_DIM 8192
#define NCELL 32768
#define DT 0.5f

// One 64-lane wave per row of W. Lane i reads float4s at stride 64 -> fully
// coalesced 1KB/wave/instruction. ec (32KB) is cache-resident.
__global__ __launch_bounds__(256) void dentate_gyrus_spike_kernel(
    const float* __restrict__ ec,
    const float* __restrict__ W,
    const float* __restrict__ v_in,
    const float* __restrict__ u_in,
    float* __restrict__ out)
{
    const int wave = threadIdx.x >> 6;      // 0..3
    const int lane = threadIdx.x & 63;
    const int row  = blockIdx.x * 4 + wave; // 8192 blocks * 4 waves = 32768 rows

    const float4* __restrict__ Wrow =
        reinterpret_cast<const float4*>(W + (size_t)row * ENTRY_DIM);
    const float4* __restrict__ ec4 = reinterpret_cast<const float4*>(ec);

    float acc = 0.0f;
    // 8192 floats / (64 lanes * 4 floats) = 32 iterations
    #pragma unroll 8
    for (int it = 0; it < 32; ++it) {
        float4 w = Wrow[it * 64 + lane];
        float4 e = ec4[it * 64 + lane];
        acc += w.x * e.x + w.y * e.y + w.z * e.z + w.w * e.w;
    }

    // wave64 butterfly reduction
    #pragma unroll
    for (int off = 32; off > 0; off >>= 1)
        acc += __shfl_down(acc, off, 64);

    if (lane == 0) {
        const float I = acc * 10.0f;                 // mossy fiber drive
        const float v = v_in[row];
        const float u = u_in[row];
        const float dv = 0.04f * v * v + 5.0f * v + 140.0f - u + I;
        const float v_new = v + dv * DT;
        // binary spike; top-k sparsification is an identity on a binary vector
        out[row] = (v_new >= 30.0f) ? 1.0f : 0.0f;
    }
}

extern "C" void kernel_launch(void* const* d_in, const int* in_sizes, int n_in,
                              void* d_out, int out_size, void* d_ws, size_t ws_size,
                              hipStream_t stream) {
    const float* ec = (const float*)d_in[0];   // (8192,)
    const float* W  = (const float*)d_in[1];   // (32768, 8192)
    const float* v  = (const float*)d_in[2];   // membrane_potential
    const float* u  = (const float*)d_in[3];   // recovery_variable
    float* out = (float*)d_out;                // (32768,) fp32 spikes

    dim3 grid(NCELL / 4);   // 4 rows (waves) per 256-thread block
    dim3 block(256);
    hipLaunchKernelGGL(dentate_gyrus_spike_kernel, grid, block, 0, stream,
                       ec, W, v, u, out);
}

// Round 3
// 161.546 us; speedup vs baseline: 1.1098x; 1.1098x over previous
//
#include <hip/hip_runtime.h>

#define ENTRY_DIM 8192
#define NCELL 32768
#define DT 0.5f

typedef float f32x4 __attribute__((ext_vector_type(4)));

// One 64-lane wave per row of W. Lane i reads float4s at stride 64 -> fully
// coalesced 1KB/wave/instruction. W is streamed once -> nontemporal loads
// (cache-bypass hint) so ec (32KB, reused 32768x) and v/u stay cache-resident.
__global__ __launch_bounds__(256) void dentate_gyrus_spike_kernel(
    const float* __restrict__ ec,
    const float* __restrict__ W,
    const float* __restrict__ v_in,
    const float* __restrict__ u_in,
    float* __restrict__ out)
{
    const int wave = threadIdx.x >> 6;      // 0..3
    const int lane = threadIdx.x & 63;
    const int row  = blockIdx.x * 4 + wave; // 8192 blocks * 4 waves = 32768 rows

    // Hoist the scalar state loads so their latency hides under the GEMV.
    const float v = v_in[row];
    const float u = u_in[row];

    const f32x4* __restrict__ Wrow =
        reinterpret_cast<const f32x4*>(W + (size_t)row * ENTRY_DIM);
    const f32x4* __restrict__ ec4 = reinterpret_cast<const f32x4*>(ec);

    float acc = 0.0f;
    // 8192 floats / (64 lanes * 4 floats) = 32 iterations
    #pragma unroll 8
    for (int it = 0; it < 32; ++it) {
        f32x4 w = __builtin_nontemporal_load(&Wrow[it * 64 + lane]);
        f32x4 e = ec4[it * 64 + lane];
        acc += w.x * e.x + w.y * e.y + w.z * e.z + w.w * e.w;
    }

    // wave64 butterfly reduction
    #pragma unroll
    for (int off = 32; off > 0; off >>= 1)
        acc += __shfl_down(acc, off, 64);

    if (lane == 0) {
        const float I = acc * 10.0f;                 // mossy fiber drive
        const float dv = 0.04f * v * v + 5.0f * v + 140.0f - u + I;
        const float v_new = v + dv * DT;
        // binary spike; top-k sparsification is an identity on a binary vector
        out[row] = (v_new >= 30.0f) ? 1.0f : 0.0f;
    }
}

extern "C" void kernel_launch(void* const* d_in, const int* in_sizes, int n_in,
                              void* d_out, int out_size, void* d_ws, size_t ws_size,
                              hipStream_t stream) {
    const float* ec = (const float*)d_in[0];   // (8192,)
    const float* W  = (const float*)d_in[1];   // (32768, 8192)
    const float* v  = (const float*)d_in[2];   // membrane_potential
    const float* u  = (const float*)d_in[3];   // recovery_variable
    float* out = (float*)d_out;                // (32768,) fp32 spikes

    dim3 grid(NCELL / 4);   // 4 rows (waves) per 256-thread block
    dim3 block(256);
    hipLaunchKernelGGL(dentate_gyrus_spike_kernel, grid, block, 0, stream,
                       ec, W, v, u, out);
}